// Round 22
// baseline (129.336 us; speedup 1.0000x reference)
//
#include <hip/hip_runtime.h>
#include <hip/hip_bf16.h>
#include <math.h>

#define LL   4096
#define DD   1280
#define HH   16
#define HDD  80
#define QKVN (3 * DD)   // 3840

typedef __attribute__((ext_vector_type(8))) short sv8;
typedef __attribute__((ext_vector_type(4))) short sv4;
typedef __attribute__((ext_vector_type(4))) float fv4;

// 16x16x16 bf16 MFMA: device pass has the builtin; host pass sees a
// __device__ stub (never codegen'd -- only needs to pass semantic checks).
#if __has_builtin(__builtin_amdgcn_mfma_f32_16x16x16bf16_1k)
#define MFMA16(a, b, c) __builtin_amdgcn_mfma_f32_16x16x16bf16_1k(a, b, c, 0, 0, 0)
#elif __has_builtin(__builtin_amdgcn_mfma_f32_16x16x16_bf16)
#define MFMA16(a, b, c) __builtin_amdgcn_mfma_f32_16x16x16_bf16(a, b, c, 0, 0, 0)
#else
__device__ static inline fv4 MFMA16(sv4, sv4, fv4 c) { return c; }   // host-pass stub
#endif

// raw v_exp_f32 (exp2f libcall has guard-code bloat without fast-math)
#if __has_builtin(__builtin_amdgcn_exp2f)
#define EXP2F(x) __builtin_amdgcn_exp2f(x)
#else
#define EXP2F(x) exp2f(x)
#endif

#define SETPRIO(n) __builtin_amdgcn_s_setprio(n)
#define SCHEDB()   __builtin_amdgcn_sched_barrier(0)

static __device__ __forceinline__ unsigned short f2bf(float f) {
  unsigned int u = __builtin_bit_cast(unsigned int, f);
  u += 0x7FFF + ((u >> 16) & 1);   // RNE
  return (unsigned short)(u >> 16);
}
static __device__ __forceinline__ float bf2f(unsigned short b) {
  unsigned int u = ((unsigned int)b) << 16;
  return __builtin_bit_cast(float, u);
}
// packed f32x2 -> bf16x2 via HW v_cvt_pk_bf16_f32 (m240: compiler path)
static __device__ __forceinline__ unsigned int cvt_pk_bf16(float lo, float hi) {
  __hip_bfloat162 h = __float22bfloat162_rn(make_float2(lo, hi));
  unsigned int u;
  __builtin_memcpy(&u, &h, 4);
  return u;
}

#define GLD_LDS(gsrc, ldst)                                                          \
  __builtin_amdgcn_global_load_lds(                                                  \
      (const __attribute__((address_space(1))) unsigned int*)(gsrc),                 \
      (__attribute__((address_space(3))) unsigned int*)(ldst), 16, 0, 0)

// ---------------------------------------------------------------------------
// fused f32 -> bf16 cast of x, Wqkv, Wproj (one launch)
// ---------------------------------------------------------------------------
__global__ __launch_bounds__(256) void cast3_kernel(
    const float* __restrict__ x, const float* __restrict__ w1,
    const float* __restrict__ w2, unsigned short* __restrict__ xb,
    unsigned short* __restrict__ w1b, unsigned short* __restrict__ w2b) {
  const int n0 = LL * DD / 8, n1 = QKVN * DD / 8, n2 = DD * DD / 8;
  int i = blockIdx.x * 256 + threadIdx.x;
  const float* in; unsigned short* out; int j;
  if (i < n0)           { in = x;  out = xb;  j = i; }
  else if (i < n0 + n1) { in = w1; out = w1b; j = i - n0; }
  else if (i < n0 + n1 + n2) { in = w2; out = w2b; j = i - n0 - n1; }
  else return;
  const float4* p = (const float4*)(in + (size_t)j * 8);
  float4 v0 = p[0], v1 = p[1];
  union { sv8 v; unsigned int u[4]; } o;
  o.u[0] = cvt_pk_bf16(v0.x, v0.y);
  o.u[1] = cvt_pk_bf16(v0.z, v0.w);
  o.u[2] = cvt_pk_bf16(v1.x, v1.y);
  o.u[3] = cvt_pk_bf16(v1.z, v1.w);
  *(sv8*)(out + (size_t)j * 8) = o.v;
}

// ---------------------------------------------------------------------------
// 256x256 bf16 NT MFMA GEMM (QKV): C = A @ B^T + bias.
// BK=32, QUAD-buffered LDS (128KB, occupancy unchanged: already 1 block/CU),
// 512 threads / 8 waves, one barrier per K-step, counted vmcnt with 3-DEEP
// prefetch: in-flight = min(3, NT-t) tiles -> vmcnt(8)/(4)/(0) ladder so
// tile t is always verified landed. Store target (r+3)&3 held tile t-1,
// whose reads were consumed before this iteration's barrier (same safety
// argument as the triple-buffer version). Epilogue: q/k planes -> qkvb,
// v plane (bn >= 2560) -> Vp 4-key units directly.
// ---------------------------------------------------------------------------
__global__ __launch_bounds__(512, 2) void gemm256_bf16_kernel(
    const unsigned short* __restrict__ A, const unsigned short* __restrict__ B,
    const float* __restrict__ bias, unsigned short* __restrict__ C,
    unsigned short* __restrict__ Vp, int M, int N, int K) {
  __shared__ __attribute__((aligned(16))) unsigned short As[4][256 * 32];
  __shared__ __attribute__((aligned(16))) unsigned short Bs[4][256 * 32];
  int tid = threadIdx.x, w = tid >> 6, lane = tid & 63;
  int g = lane >> 4, l15 = lane & 15;
  int wr = w >> 2, wc = w & 3;           // 2 x 4 wave grid

  // XCD-bijective swizzle: 240 blocks = 8 XCDs x 30 (2 full M-rows each)
  int bid = blockIdx.x;
  int wg = (bid & 7) * 30 + (bid >> 3);
  int bm = (wg / 15) * 256;
  int bn = (wg % 15) * 256;

  fv4 acc[8][4];
#pragma unroll
  for (int a = 0; a < 8; ++a)
#pragma unroll
    for (int b = 0; b < 4; ++b) acc[a][b] = (fv4){0.f, 0.f, 0.f, 0.f};

  auto STAGE = [&](int buf, int t) {     // 4 loads per wave (32 chunks total)
    int k0 = t * 32;
#pragma unroll
    for (int i = 0; i < 4; ++i) {
      int cid = w * 4 + i;               // 0..31 ; 0..15 = A, 16..31 = B
      int c = cid & 15;
      int row = c * 16 + (lane >> 2);
      int gsrc = (lane & 3) ^ ((row >> 1) & 3);
      const unsigned short* src = (cid < 16)
          ? A + (size_t)(bm + row) * K + k0 + gsrc * 8
          : B + (size_t)(bn + row) * K + k0 + gsrc * 8;
      unsigned short* dst = ((cid < 16) ? As[buf] : Bs[buf]) + c * 512;
      GLD_LDS(src, dst);
    }
  };

  const int NT = 40;                     // K/32
  int r = 0;
  STAGE(0, 0);
  STAGE(1, 1);
  STAGE(2, 2);
  for (int t = 0; t < NT; ++t) {
    if (t + 3 <= NT)      asm volatile("s_waitcnt vmcnt(8)" ::: "memory");
    else if (t + 2 <= NT) asm volatile("s_waitcnt vmcnt(4)" ::: "memory");
    else                  asm volatile("s_waitcnt vmcnt(0)" ::: "memory");
    SCHEDB();
    asm volatile("s_barrier" ::: "memory");
    // stage t+3 into the buffer read at t-1 (its readers all passed barrier)
    if (t + 3 < NT) STAGE((r + 3) & 3, t + 3);

    const unsigned short* Ab = As[r];
    const unsigned short* Bb = Bs[r];
    sv8 af[4], bfr[4];
    // ---- phase 1: B frags + A rows 0..63 ----
#pragma unroll
    for (int nt = 0; nt < 4; ++nt) {
      int row = wc * 64 + nt * 16 + l15;
      bfr[nt] = *(const sv8*)(Bb + row * 32 + ((g ^ ((row >> 1) & 3)) * 8));
    }
#pragma unroll
    for (int mt = 0; mt < 4; ++mt) {
      int row = wr * 128 + mt * 16 + l15;
      af[mt] = *(const sv8*)(Ab + row * 32 + ((g ^ ((row >> 1) & 3)) * 8));
    }
    SCHEDB();
    SETPRIO(1);
#pragma unroll
    for (int mt = 0; mt < 4; ++mt)
#pragma unroll
      for (int nt = 0; nt < 4; ++nt)
        acc[mt][nt] = __builtin_amdgcn_mfma_f32_16x16x32_bf16(af[mt], bfr[nt], acc[mt][nt], 0, 0, 0);
    SETPRIO(0);
    SCHEDB();
    // ---- phase 2: A rows 64..127 ----
    sv8 af2[4];
#pragma unroll
    for (int mt = 0; mt < 4; ++mt) {
      int row = wr * 128 + (mt + 4) * 16 + l15;
      af2[mt] = *(const sv8*)(Ab + row * 32 + ((g ^ ((row >> 1) & 3)) * 8));
    }
    SCHEDB();
    SETPRIO(1);
#pragma unroll
    for (int mt = 0; mt < 4; ++mt)
#pragma unroll
      for (int nt = 0; nt < 4; ++nt)
        acc[mt + 4][nt] = __builtin_amdgcn_mfma_f32_16x16x32_bf16(af2[mt], bfr[nt], acc[mt + 4][nt], 0, 0, 0);
    SETPRIO(0);
    r = (r + 1) & 3;
  }

  if (bn < 2560) {
    // q/k planes: row-major qkvb store (pack_qk consumes these)
#pragma unroll
    for (int mt = 0; mt < 8; ++mt)
#pragma unroll
      for (int nt = 0; nt < 4; ++nt) {
        int n = bn + wc * 64 + nt * 16 + l15;
        float bv = bias[n];
#pragma unroll
        for (int rr = 0; rr < 4; ++rr) {
          int m = bm + wr * 128 + mt * 16 + 4 * g + rr;
          C[(size_t)m * N + n] = f2bf(acc[mt][nt][rr] + bv);
        }
      }
  } else {
    // v plane: direct Vp[h][blk][ntg16][d80] 4-key-unit store
#pragma unroll
    for (int mt = 0; mt < 8; ++mt)
#pragma unroll
      for (int nt = 0; nt < 4; ++nt) {
        int n = bn + wc * 64 + nt * 16 + l15;
        int v = n - 2560;
        int h = v / HDD, d = v % HDD;
        float bv = bias[n];
        int m0 = bm + wr * 128 + mt * 16 + 4 * g;   // m0 % 4 == 0
        int blk = m0 >> 6, ntg = (m0 >> 2) & 15;
        uint2 pk;
        pk.x = cvt_pk_bf16(acc[mt][nt][0] + bv, acc[mt][nt][1] + bv);
        pk.y = cvt_pk_bf16(acc[mt][nt][2] + bv, acc[mt][nt][3] + bv);
        size_t unit = (((size_t)h * 64 + blk) * 16 + ntg) * HDD + d;
        *(uint2*)(Vp + unit * 4) = pk;
      }
  }
}

// ---------------------------------------------------------------------------
// bf16 NT MFMA GEMM (proj): 128x128 tile, BK=64, counted vmcnt dbuf.
// setprio around each 16-MFMA cluster. (320 blocks, 4 blocks/CU capacity --
// the 256x128/160-block variant regressed on grid under-fill.)
// ---------------------------------------------------------------------------
__global__ __launch_bounds__(256) void gemm_bf16_kernel(
    const unsigned short* __restrict__ A, const unsigned short* __restrict__ B,
    const float* __restrict__ bias, void* __restrict__ Cv,
    int M, int N, int K, int out_bf16) {
  __shared__ __attribute__((aligned(16))) unsigned short As[2][128 * 64];
  __shared__ __attribute__((aligned(16))) unsigned short Bs[2][128 * 64];
  int tid = threadIdx.x, w = tid >> 6, lane = tid & 63;
  int g = lane >> 4, l15 = lane & 15;
  int wr = w >> 1, wc = w & 1;
  int bm = blockIdx.y * 128, bn = blockIdx.x * 128;

  fv4 acc[4][4];
#pragma unroll
  for (int a = 0; a < 4; ++a)
#pragma unroll
    for (int b = 0; b < 4; ++b) acc[a][b] = (fv4){0.f, 0.f, 0.f, 0.f};

  auto STAGE = [&](int buf, int k0) {   // 8 loads per wave
#pragma unroll
    for (int i = 0; i < 4; ++i) {
      int c = w * 4 + i;
      int row = 8 * c + (lane >> 3);
      int cb = lane & 7;
      int gcol = k0 + ((cb ^ (row & 7)) * 8);
      GLD_LDS(A + (size_t)(bm + row) * K + gcol, As[buf] + c * 512);
      GLD_LDS(B + (size_t)(bn + row) * K + gcol, Bs[buf] + c * 512);
    }
  };

  int nt = K / 64, cur = 0;
  STAGE(0, 0);
  if (nt > 1) STAGE(1, 64);
  for (int t = 0; t < nt; ++t) {
    if (t + 1 < nt) asm volatile("s_waitcnt vmcnt(8)" ::: "memory");
    else            asm volatile("s_waitcnt vmcnt(0)" ::: "memory");
    SCHEDB();
    asm volatile("s_barrier" ::: "memory");
    const unsigned short* Ab = As[cur];
    const unsigned short* Bb = Bs[cur];
#pragma unroll
    for (int s = 0; s < 2; ++s) {
      sv8 af[4], bf[4];
#pragma unroll
      for (int t4 = 0; t4 < 4; ++t4) {
        int ra = wr * 64 + t4 * 16 + l15;
        af[t4] = *(const sv8*)(Ab + ra * 64 + (((s * 4 + g) ^ (ra & 7)) * 8));
        int rb = wc * 64 + t4 * 16 + l15;
        bf[t4] = *(const sv8*)(Bb + rb * 64 + (((s * 4 + g) ^ (rb & 7)) * 8));
      }
      SCHEDB();
      SETPRIO(1);
#pragma unroll
      for (int mt = 0; mt < 4; ++mt)
#pragma unroll
        for (int nt2 = 0; nt2 < 4; ++nt2)
          acc[mt][nt2] = __builtin_amdgcn_mfma_f32_16x16x32_bf16(af[mt], bf[nt2], acc[mt][nt2], 0, 0, 0);
      SETPRIO(0);
      SCHEDB();
    }
    asm volatile("s_waitcnt lgkmcnt(0)" ::: "memory");
    asm volatile("s_barrier" ::: "memory");     // all waves done reading buf[cur]
    if (t + 2 < nt) STAGE(cur, (t + 2) * 64);
    cur ^= 1;
  }

  if (out_bf16) {
    unsigned short* C = (unsigned short*)Cv;
#pragma unroll
    for (int mt = 0; mt < 4; ++mt)
#pragma unroll
      for (int nt2 = 0; nt2 < 4; ++nt2)
#pragma unroll
        for (int r = 0; r < 4; ++r) {
          int m = bm + wr * 64 + mt * 16 + 4 * g + r;
          int n = bn + wc * 64 + nt2 * 16 + l15;
          C[(size_t)m * N + n] = f2bf(acc[mt][nt2][r] + bias[n]);
        }
  } else {
    float* C = (float*)Cv;
#pragma unroll
    for (int mt = 0; mt < 4; ++mt)
#pragma unroll
      for (int nt2 = 0; nt2 < 4; ++nt2)
#pragma unroll
        for (int r = 0; r < 4; ++r) {
          int m = bm + wr * 64 + mt * 16 + 4 * g + r;
          int n = bn + wc * 64 + nt2 * 16 + l15;
          C[(size_t)m * N + n] = acc[mt][nt2][r] + bias[n];
        }
  }
}

// ---------------------------------------------------------------------------
// pack_qk: rope + scale(q, incl. log2e) + bf16.
// Qb[h][l][80]; K split: Kmain[h][l][64] (d 0..63) + Ktail[h][blk][tg4][key64]
// in 8-byte units (d 64..79, tg = (d-64)/4).
// ---------------------------------------------------------------------------
__global__ __launch_bounds__(192) void pack_qk_kernel(
    const unsigned short* __restrict__ qkvb, const float* __restrict__ freqs,
    unsigned short* __restrict__ Qb, unsigned short* __restrict__ Kmain,
    unsigned short* __restrict__ Ktail) {
  int l = blockIdx.x;
  __shared__ float cs[40], sn[40];
  if (threadIdx.x < 40) {
    float f = freqs[(size_t)l * 40 + threadIdx.x];
    cs[threadIdx.x] = cosf(f);
    sn[threadIdx.x] = sinf(f);
  }
  __syncthreads();
  int t = threadIdx.x;
  if (t >= 160) return;
  int which = t / 80;              // 0 = q, 1 = k
  int rem   = t % 80;
  int h = rem / 5, pg = rem % 5;
  int d0 = pg * 8;
  const unsigned short* src = qkvb + (size_t)l * QKVN + which * DD + h * HDD;
  union { sv8 v; unsigned short u[8]; } A, B;
  A.v = *(const sv8*)(src + d0);
  B.v = *(const sv8*)(src + d0 + 40);
  float scale = which ? 1.0f : 0.16129822676f;   // q: 1/sqrt(80)*log2(e)
  float lo[8], hi[8];
#pragma unroll
  for (int j = 0; j < 8; ++j) {
    float c = cs[d0 + j], s = sn[d0 + j];
    float a = bf2f(A.u[j]), b = bf2f(B.u[j]);
    lo[j] = (a * c - b * s) * scale;
    hi[j] = (b * c + a * s) * scale;
  }
  union { sv8 v; unsigned int u[4]; } OL, OH;
#pragma unroll
  for (int j = 0; j < 4; ++j) {
    OL.u[j] = cvt_pk_bf16(lo[2 * j], lo[2 * j + 1]);
    OH.u[j] = cvt_pk_bf16(hi[2 * j], hi[2 * j + 1]);
  }
  if (which == 0) {
    unsigned short* dst = Qb + ((size_t)h * LL + l) * HDD;
    *(sv8*)(dst + d0) = OL.v;
    *(sv8*)(dst + d0 + 40) = OH.v;
  } else {
    unsigned short* km = Kmain + ((size_t)h * LL + l) * 64;
    *(sv8*)(km + pg * 8) = OL.v;                 // d0 in 0..32 (main)
    int dh = d0 + 40;
    if (dh < 64) {
      *(sv8*)(km + dh) = OH.v;                   // dh 40,48,56 (main)
    } else {
      // tail: dh = 64 or 72 -> tg0 = (dh-64)/4, units (tg0, tg0+1)
      int blk = l >> 6, key = l & 63;
      int tg0 = (dh - 64) >> 2;
      size_t base = (((size_t)h * 64 + blk) * 4);
      uint2 w0 = make_uint2(OH.u[0], OH.u[1]);   // d dh..dh+3
      uint2 w1 = make_uint2(OH.u[2], OH.u[3]);   // d dh+4..dh+7
      *(uint2*)(Ktail + ((base + tg0) * 64 + key) * 4)     = w0;
      *(uint2*)(Ktail + ((base + tg0 + 1) * 64 + key) * 4) = w1;
    }
  }
}

// ---------------------------------------------------------------------------
// Flash attention: swapped QK^T, exp2-space softmax (no online max),
// in-register P -> PV via 16x16x16 MFMA. Conflict-free LDS. Raw v_exp_f32.
// setprio(1) spans the QK^T->PV compute region. 64 q rows per block,
// 1024 blocks, counted vmcnt(5), 40KB LDS.
// ---------------------------------------------------------------------------
__global__ __launch_bounds__(256) void attn_mfma_kernel(
    const unsigned short* __restrict__ Qb,     // [H][L][80] (pre-scaled)
    const unsigned short* __restrict__ Kmain,  // [H][L][64]
    const unsigned short* __restrict__ Ktail,  // [H][64][4][64] 8B units
    const unsigned short* __restrict__ Vp,     // [H][64][16][80] 8B units
    const int* __restrict__ cu,
    unsigned short* __restrict__ outb) {       // [L][1280] bf16
  __shared__ __attribute__((aligned(16))) unsigned short Ks[2][64 * 64];
  __shared__ __attribute__((aligned(16))) unsigned short Kt[2][4 * 64 * 4];
  __shared__ __attribute__((aligned(16))) unsigned short Vl[2][16 * 80 * 4];
  int tid = threadIdx.x, w = tid >> 6, lane = tid & 63;
  int g = lane >> 4, l15 = lane & 15;

  // XCD-aware bijective swizzle: 1024 blocks, 8 XCDs -> 2 whole heads per XCD
  int bid = blockIdx.x;
  int sw = (bid & 7) * 128 + (bid >> 3);
  int h = sw >> 6;
  int q0 = (sw & 63) * 64;

  int s0 = 0, s1 = LL;
#pragma unroll
  for (int i = 0; i < 4; ++i) {
    int a = cu[i], b = cu[i + 1];
    if (q0 >= a && q0 < b) { s0 = a; s1 = b; }
  }

  // Q fragments (B operand: col=l15=q). rows = q0 + w*16 + l15
  int qrow = q0 + w * 16 + l15;
  const unsigned short* qp = Qb + ((size_t)h * LL + qrow) * HDD;
  sv8 aq[2];
#pragma unroll
  for (int s = 0; s < 2; ++s) aq[s] = *(const sv8*)(qp + s * 32 + g * 8);
  union { sv4 v; uint2 u2; } qt;           // Q tail dims 64..79 (K=16 B-frag)
  qt.u2 = *(const uint2*)(qp + 64 + 4 * g);

  auto STAGE = [&](int buf, int kb) {      // 5 loads per wave (uniform)
    int blk = kb >> 6;
#pragma unroll
    for (int i = 0; i < 5; ++i) {
      int cid = w + 4 * i;                 // 0..19
      if (cid < 8) {                       // Kmain chunk: 8 rows of 128B
        int row = 8 * cid + (lane >> 3);
        int cb = lane & 7;
        GLD_LDS(Kmain + ((size_t)h * LL + kb + row) * 64 + ((cb ^ (row & 7)) * 8),
                Ks[buf] + cid * 512);
      } else if (cid < 10) {               // Ktail: 2 chunks, linear units
        int tc = cid - 8;
        GLD_LDS(Ktail + ((((size_t)h * 64 + blk) * 256) + tc * 128 + 2 * lane) * 4,
                Kt[buf] + tc * 512);
      } else {                             // V: 10 chunks, linear units
        int vc = cid - 10;
        GLD_LDS(Vp + ((((size_t)h * 64 + blk) * 1280) + vc * 128 + 2 * lane) * 4,
                Vl[buf] + vc * 512);
      }
    }
  };

  fv4 o[5];
#pragma unroll
  for (int dt = 0; dt < 5; ++dt) o[dt] = (fv4){0.f, 0.f, 0.f, 0.f};
  float lsum = 0.f;

  int cur = 0;
  STAGE(0, s0);
  if (s0 + 64 < s1) STAGE(1, s0 + 64);
  for (int kb = s0; kb < s1; kb += 64) {
    if (kb + 64 < s1) asm volatile("s_waitcnt vmcnt(5)" ::: "memory");
    else              asm volatile("s_waitcnt vmcnt(0)" ::: "memory");
    SCHEDB();
    asm volatile("s_barrier" ::: "memory");
    const unsigned short* Kc = Ks[cur];
    const unsigned short* Ktc = Kt[cur];
    const unsigned short* Vc = Vl[cur];

    SETPRIO(1);
    // S^T = K Q^T : D[row=key_local][col=q]
    fv4 sf[4];
#pragma unroll
    for (int nt = 0; nt < 4; ++nt) sf[nt] = (fv4){0.f, 0.f, 0.f, 0.f};
#pragma unroll
    for (int s = 0; s < 2; ++s) {
#pragma unroll
      for (int nt = 0; nt < 4; ++nt) {
        int key = nt * 16 + l15;
        sv8 ak = *(const sv8*)(Kc + key * 64 + (((s * 4 + g) ^ (key & 7)) * 8));
        sf[nt] = __builtin_amdgcn_mfma_f32_16x16x32_bf16(ak, aq[s], sf[nt], 0, 0, 0);
      }
    }
#pragma unroll
    for (int nt = 0; nt < 4; ++nt) {       // dims 64..79 via K=16 MFMA
      sv4 akt = *(const sv4*)(Ktc + (g * 64 + nt * 16 + l15) * 4);
      sf[nt] = MFMA16(akt, qt.v, sf[nt]);
    }

    // P = exp2(S^T) stays in-register (C-frag == 16x16x16 A-frag)
#pragma unroll
    for (int nt = 0; nt < 4; ++nt) {
      float p0 = EXP2F(sf[nt][0]);
      float p1 = EXP2F(sf[nt][1]);
      float p2 = EXP2F(sf[nt][2]);
      float p3 = EXP2F(sf[nt][3]);
      lsum += (p0 + p1) + (p2 + p3);
      union { sv4 v; unsigned int u[2]; } pa;
      pa.u[0] = cvt_pk_bf16(p0, p1);
      pa.u[1] = cvt_pk_bf16(p2, p3);
#pragma unroll
      for (int dt = 0; dt < 5; ++dt) {
        sv4 vb4 = *(const sv4*)(Vc + ((nt * 4 + g) * 80 + dt * 16 + l15) * 4);
        o[dt] = MFMA16(pa.v, vb4, o[dt]);
      }
    }
    SETPRIO(0);
    asm volatile("s_waitcnt lgkmcnt(0)" ::: "memory");
    asm volatile("s_barrier" ::: "memory");
    if (kb + 128 < s1) STAGE(cur, kb + 128);
    cur ^= 1;
  }

  // epilogue: reduce lsum across g (all lanes same l15 -> total), route by row
  lsum += __shfl_xor(lsum, 16);
  lsum += __shfl_xor(lsum, 32);
  float inv = 1.f / lsum;
#pragma unroll
  for (int r = 0; r < 4; ++r) {
    float invr = __shfl(inv, 4 * g + r);   // lane with l15 == 4g+r
    int row = q0 + w * 16 + 4 * g + r;
#pragma unroll
    for (int dt = 0; dt < 5; ++dt) {
      outb[(size_t)row * DD + h * HDD + dt * 16 + l15] = f2bf(o[dt][r] * invr);
    }
  }
}

// ---------------------------------------------------------------------------
extern "C" void kernel_launch(void* const* d_in, const int* in_sizes, int n_in,
                              void* d_out, int out_size, void* d_ws, size_t ws_size,
                              hipStream_t stream) {
  const float* x     = (const float*)d_in[0];
  const int*   cu    = (const int*)d_in[1];
  const float* rope  = (const float*)d_in[2];
  const float* Wqkv  = (const float*)d_in[3];
  const float* bqkv  = (const float*)d_in[4];
  const float* Wproj = (const float*)d_in[5];
  const float* bproj = (const float*)d_in[6];
  float* out = (float*)d_out;

  char* ws = (char*)d_ws;
  unsigned short* qkvb   = (unsigned short*)ws;                 // 31,457,280 B (q/k planes used)
  unsigned short* attn_b = (unsigned short*)ws;                 // alias (qkvb dead by then)
  unsigned short* xb     = (unsigned short*)(ws + 31457280);    // 10,485,760
  unsigned short* Wqkvb  = (unsigned short*)(ws + 41943040);    //  9,830,400
  unsigned short* Wprojb = (unsigned short*)(ws + 51773440);    //  3,276,800
  unsigned short* Kmain  = (unsigned short*)(ws + 55050240);    //  8,388,608 ([H][L][64])
  unsigned short* Ktail  = (unsigned short*)(ws + 63438848);    //  2,097,152 ([H][64][4][64]x8B)
  unsigned short* Vp     = (unsigned short*)(ws + 65536000);    // 10,485,760 ([H][64][16][80]x8B)
  unsigned short* Qb     = xb;                                  // alias (xb dead after gemm1)

  // casts (one launch)
  {
    int n8 = LL * DD / 8 + QKVN * DD / 8 + DD * DD / 8;
    cast3_kernel<<<(n8 + 255) / 256, 256, 0, stream>>>(x, Wqkv, Wproj, xb, Wqkvb, Wprojb);
  }

  // qkv = x @ Wqkv^T + b  (bf16): q/k planes -> qkvb, v plane -> Vp directly
  gemm256_bf16_kernel<<<240, 512, 0, stream>>>(
      xb, Wqkvb, bqkv, qkvb, Vp, LL, QKVN, DD);

  // rope + pack (V already packed by the GEMM epilogue)
  pack_qk_kernel<<<LL, 192, 0, stream>>>(qkvb, rope, Qb, Kmain, Ktail);

  // attention
  attn_mfma_kernel<<<1024, 256, 0, stream>>>(Qb, Kmain, Ktail, Vp, cu, attn_b);

  // out = attn @ Wproj^T + b  (fp32 out): 128^2 tile, 320 blocks
  gemm_bf16_kernel<<<dim3(DD / 128, LL / 128), 256, 0, stream>>>(
      attn_b, Wprojb, bproj, out, LL, DD, DD, 0);
}

// Round 23
// 129.065 us; speedup vs baseline: 1.0021x; 1.0021x over previous
//
#include <hip/hip_runtime.h>
#include <hip/hip_bf16.h>
#include <math.h>

#define LL   4096
#define DD   1280
#define HH   16
#define HDD  80
#define QKVN (3 * DD)   // 3840

typedef __attribute__((ext_vector_type(8))) short sv8;
typedef __attribute__((ext_vector_type(4))) short sv4;
typedef __attribute__((ext_vector_type(4))) float fv4;

// 16x16x16 bf16 MFMA: device pass has the builtin; host pass sees a
// __device__ stub (never codegen'd -- only needs to pass semantic checks).
#if __has_builtin(__builtin_amdgcn_mfma_f32_16x16x16bf16_1k)
#define MFMA16(a, b, c) __builtin_amdgcn_mfma_f32_16x16x16bf16_1k(a, b, c, 0, 0, 0)
#elif __has_builtin(__builtin_amdgcn_mfma_f32_16x16x16_bf16)
#define MFMA16(a, b, c) __builtin_amdgcn_mfma_f32_16x16x16_bf16(a, b, c, 0, 0, 0)
#else
__device__ static inline fv4 MFMA16(sv4, sv4, fv4 c) { return c; }   // host-pass stub
#endif

// raw v_exp_f32 (exp2f libcall has guard-code bloat without fast-math)
#if __has_builtin(__builtin_amdgcn_exp2f)
#define EXP2F(x) __builtin_amdgcn_exp2f(x)
#else
#define EXP2F(x) exp2f(x)
#endif

#define SETPRIO(n) __builtin_amdgcn_s_setprio(n)
#define SCHEDB()   __builtin_amdgcn_sched_barrier(0)

static __device__ __forceinline__ unsigned short f2bf(float f) {
  unsigned int u = __builtin_bit_cast(unsigned int, f);
  u += 0x7FFF + ((u >> 16) & 1);   // RNE
  return (unsigned short)(u >> 16);
}
static __device__ __forceinline__ float bf2f(unsigned short b) {
  unsigned int u = ((unsigned int)b) << 16;
  return __builtin_bit_cast(float, u);
}
// packed f32x2 -> bf16x2 via HW v_cvt_pk_bf16_f32 (m240: compiler path)
static __device__ __forceinline__ unsigned int cvt_pk_bf16(float lo, float hi) {
  __hip_bfloat162 h = __float22bfloat162_rn(make_float2(lo, hi));
  unsigned int u;
  __builtin_memcpy(&u, &h, 4);
  return u;
}

#define GLD_LDS(gsrc, ldst)                                                          \
  __builtin_amdgcn_global_load_lds(                                                  \
      (const __attribute__((address_space(1))) unsigned int*)(gsrc),                 \
      (__attribute__((address_space(3))) unsigned int*)(ldst), 16, 0, 0)

// ---------------------------------------------------------------------------
// fused f32 -> bf16 cast of x, Wqkv, Wproj (one launch)
// ---------------------------------------------------------------------------
__global__ __launch_bounds__(256) void cast3_kernel(
    const float* __restrict__ x, const float* __restrict__ w1,
    const float* __restrict__ w2, unsigned short* __restrict__ xb,
    unsigned short* __restrict__ w1b, unsigned short* __restrict__ w2b) {
  const int n0 = LL * DD / 8, n1 = QKVN * DD / 8, n2 = DD * DD / 8;
  int i = blockIdx.x * 256 + threadIdx.x;
  const float* in; unsigned short* out; int j;
  if (i < n0)           { in = x;  out = xb;  j = i; }
  else if (i < n0 + n1) { in = w1; out = w1b; j = i - n0; }
  else if (i < n0 + n1 + n2) { in = w2; out = w2b; j = i - n0 - n1; }
  else return;
  const float4* p = (const float4*)(in + (size_t)j * 8);
  float4 v0 = p[0], v1 = p[1];
  union { sv8 v; unsigned int u[4]; } o;
  o.u[0] = cvt_pk_bf16(v0.x, v0.y);
  o.u[1] = cvt_pk_bf16(v0.z, v0.w);
  o.u[2] = cvt_pk_bf16(v1.x, v1.y);
  o.u[3] = cvt_pk_bf16(v1.z, v1.w);
  *(sv8*)(out + (size_t)j * 8) = o.v;
}

// ---------------------------------------------------------------------------
// 256x256 bf16 NT MFMA GEMM (QKV): C = A @ B^T + bias.
// BK=32, triple-buffered LDS, 512 threads / 8 waves, one barrier per K-step,
// counted vmcnt(4) with 2-deep prefetch. Epilogue: q/k planes -> qkvb,
// v plane (bn >= 2560) -> Vp 4-key units directly. (Best measured config:
// 47.0us; quad-buffer 3-deep was null, phase-splits/anti-phase regressed.)
// ---------------------------------------------------------------------------
__global__ __launch_bounds__(512, 2) void gemm256_bf16_kernel(
    const unsigned short* __restrict__ A, const unsigned short* __restrict__ B,
    const float* __restrict__ bias, unsigned short* __restrict__ C,
    unsigned short* __restrict__ Vp, int M, int N, int K) {
  __shared__ __attribute__((aligned(16))) unsigned short As[3][256 * 32];
  __shared__ __attribute__((aligned(16))) unsigned short Bs[3][256 * 32];
  int tid = threadIdx.x, w = tid >> 6, lane = tid & 63;
  int g = lane >> 4, l15 = lane & 15;
  int wr = w >> 2, wc = w & 3;           // 2 x 4 wave grid

  // XCD-bijective swizzle: 240 blocks = 8 XCDs x 30 (2 full M-rows each)
  int bid = blockIdx.x;
  int wg = (bid & 7) * 30 + (bid >> 3);
  int bm = (wg / 15) * 256;
  int bn = (wg % 15) * 256;

  fv4 acc[8][4];
#pragma unroll
  for (int a = 0; a < 8; ++a)
#pragma unroll
    for (int b = 0; b < 4; ++b) acc[a][b] = (fv4){0.f, 0.f, 0.f, 0.f};

  auto STAGE = [&](int buf, int t) {     // 4 loads per wave (32 chunks total)
    int k0 = t * 32;
#pragma unroll
    for (int i = 0; i < 4; ++i) {
      int cid = w * 4 + i;               // 0..31 ; 0..15 = A, 16..31 = B
      int c = cid & 15;
      int row = c * 16 + (lane >> 2);
      int gsrc = (lane & 3) ^ ((row >> 1) & 3);
      const unsigned short* src = (cid < 16)
          ? A + (size_t)(bm + row) * K + k0 + gsrc * 8
          : B + (size_t)(bn + row) * K + k0 + gsrc * 8;
      unsigned short* dst = ((cid < 16) ? As[buf] : Bs[buf]) + c * 512;
      GLD_LDS(src, dst);
    }
  };

  const int NT = 40;                     // K/32
  int r = 0;
  STAGE(0, 0);
  STAGE(1, 1);
  for (int t = 0; t < NT; ++t) {
    if (t + 1 < NT) asm volatile("s_waitcnt vmcnt(4)" ::: "memory");
    else            asm volatile("s_waitcnt vmcnt(0)" ::: "memory");
    SCHEDB();
    asm volatile("s_barrier" ::: "memory");
    // stage t+2 into the buffer read at t-1 (its readers all passed barrier)
    int s2 = (r == 0) ? 2 : r - 1;
    if (t + 2 < NT) STAGE(s2, t + 2);

    const unsigned short* Ab = As[r];
    const unsigned short* Bb = Bs[r];
    sv8 af[4], bfr[4];
    // ---- phase 1: B frags + A rows 0..63 ----
#pragma unroll
    for (int nt = 0; nt < 4; ++nt) {
      int row = wc * 64 + nt * 16 + l15;
      bfr[nt] = *(const sv8*)(Bb + row * 32 + ((g ^ ((row >> 1) & 3)) * 8));
    }
#pragma unroll
    for (int mt = 0; mt < 4; ++mt) {
      int row = wr * 128 + mt * 16 + l15;
      af[mt] = *(const sv8*)(Ab + row * 32 + ((g ^ ((row >> 1) & 3)) * 8));
    }
    SCHEDB();
    SETPRIO(1);
#pragma unroll
    for (int mt = 0; mt < 4; ++mt)
#pragma unroll
      for (int nt = 0; nt < 4; ++nt)
        acc[mt][nt] = __builtin_amdgcn_mfma_f32_16x16x32_bf16(af[mt], bfr[nt], acc[mt][nt], 0, 0, 0);
    SETPRIO(0);
    SCHEDB();
    // ---- phase 2: A rows 64..127 ----
    sv8 af2[4];
#pragma unroll
    for (int mt = 0; mt < 4; ++mt) {
      int row = wr * 128 + (mt + 4) * 16 + l15;
      af2[mt] = *(const sv8*)(Ab + row * 32 + ((g ^ ((row >> 1) & 3)) * 8));
    }
    SCHEDB();
    SETPRIO(1);
#pragma unroll
    for (int mt = 0; mt < 4; ++mt)
#pragma unroll
      for (int nt = 0; nt < 4; ++nt)
        acc[mt + 4][nt] = __builtin_amdgcn_mfma_f32_16x16x32_bf16(af2[mt], bfr[nt], acc[mt + 4][nt], 0, 0, 0);
    SETPRIO(0);
    r = (r == 2) ? 0 : r + 1;
  }

  if (bn < 2560) {
    // q/k planes: row-major qkvb store (pack_qk consumes these)
#pragma unroll
    for (int mt = 0; mt < 8; ++mt)
#pragma unroll
      for (int nt = 0; nt < 4; ++nt) {
        int n = bn + wc * 64 + nt * 16 + l15;
        float bv = bias[n];
#pragma unroll
        for (int rr = 0; rr < 4; ++rr) {
          int m = bm + wr * 128 + mt * 16 + 4 * g + rr;
          C[(size_t)m * N + n] = f2bf(acc[mt][nt][rr] + bv);
        }
      }
  } else {
    // v plane: direct Vp[h][blk][ntg16][d80] 4-key-unit store
#pragma unroll
    for (int mt = 0; mt < 8; ++mt)
#pragma unroll
      for (int nt = 0; nt < 4; ++nt) {
        int n = bn + wc * 64 + nt * 16 + l15;
        int v = n - 2560;
        int h = v / HDD, d = v % HDD;
        float bv = bias[n];
        int m0 = bm + wr * 128 + mt * 16 + 4 * g;   // m0 % 4 == 0
        int blk = m0 >> 6, ntg = (m0 >> 2) & 15;
        uint2 pk;
        pk.x = cvt_pk_bf16(acc[mt][nt][0] + bv, acc[mt][nt][1] + bv);
        pk.y = cvt_pk_bf16(acc[mt][nt][2] + bv, acc[mt][nt][3] + bv);
        size_t unit = (((size_t)h * 64 + blk) * 16 + ntg) * HDD + d;
        *(uint2*)(Vp + unit * 4) = pk;
      }
  }
}

// ---------------------------------------------------------------------------
// bf16 NT MFMA GEMM (proj): 128x128 tile, BK=64, counted vmcnt dbuf.
// setprio around each 16-MFMA cluster. (320 blocks, 4 blocks/CU capacity --
// the 256x128/160-block variant regressed on grid under-fill.)
// ---------------------------------------------------------------------------
__global__ __launch_bounds__(256) void gemm_bf16_kernel(
    const unsigned short* __restrict__ A, const unsigned short* __restrict__ B,
    const float* __restrict__ bias, void* __restrict__ Cv,
    int M, int N, int K, int out_bf16) {
  __shared__ __attribute__((aligned(16))) unsigned short As[2][128 * 64];
  __shared__ __attribute__((aligned(16))) unsigned short Bs[2][128 * 64];
  int tid = threadIdx.x, w = tid >> 6, lane = tid & 63;
  int g = lane >> 4, l15 = lane & 15;
  int wr = w >> 1, wc = w & 1;
  int bm = blockIdx.y * 128, bn = blockIdx.x * 128;

  fv4 acc[4][4];
#pragma unroll
  for (int a = 0; a < 4; ++a)
#pragma unroll
    for (int b = 0; b < 4; ++b) acc[a][b] = (fv4){0.f, 0.f, 0.f, 0.f};

  auto STAGE = [&](int buf, int k0) {   // 8 loads per wave
#pragma unroll
    for (int i = 0; i < 4; ++i) {
      int c = w * 4 + i;
      int row = 8 * c + (lane >> 3);
      int cb = lane & 7;
      int gcol = k0 + ((cb ^ (row & 7)) * 8);
      GLD_LDS(A + (size_t)(bm + row) * K + gcol, As[buf] + c * 512);
      GLD_LDS(B + (size_t)(bn + row) * K + gcol, Bs[buf] + c * 512);
    }
  };

  int nt = K / 64, cur = 0;
  STAGE(0, 0);
  if (nt > 1) STAGE(1, 64);
  for (int t = 0; t < nt; ++t) {
    if (t + 1 < nt) asm volatile("s_waitcnt vmcnt(8)" ::: "memory");
    else            asm volatile("s_waitcnt vmcnt(0)" ::: "memory");
    SCHEDB();
    asm volatile("s_barrier" ::: "memory");
    const unsigned short* Ab = As[cur];
    const unsigned short* Bb = Bs[cur];
#pragma unroll
    for (int s = 0; s < 2; ++s) {
      sv8 af[4], bf[4];
#pragma unroll
      for (int t4 = 0; t4 < 4; ++t4) {
        int ra = wr * 64 + t4 * 16 + l15;
        af[t4] = *(const sv8*)(Ab + ra * 64 + (((s * 4 + g) ^ (ra & 7)) * 8));
        int rb = wc * 64 + t4 * 16 + l15;
        bf[t4] = *(const sv8*)(Bb + rb * 64 + (((s * 4 + g) ^ (rb & 7)) * 8));
      }
      SCHEDB();
      SETPRIO(1);
#pragma unroll
      for (int mt = 0; mt < 4; ++mt)
#pragma unroll
        for (int nt2 = 0; nt2 < 4; ++nt2)
          acc[mt][nt2] = __builtin_amdgcn_mfma_f32_16x16x32_bf16(af[mt], bf[nt2], acc[mt][nt2], 0, 0, 0);
      SETPRIO(0);
      SCHEDB();
    }
    asm volatile("s_waitcnt lgkmcnt(0)" ::: "memory");
    asm volatile("s_barrier" ::: "memory");     // all waves done reading buf[cur]
    if (t + 2 < nt) STAGE(cur, (t + 2) * 64);
    cur ^= 1;
  }

  if (out_bf16) {
    unsigned short* C = (unsigned short*)Cv;
#pragma unroll
    for (int mt = 0; mt < 4; ++mt)
#pragma unroll
      for (int nt2 = 0; nt2 < 4; ++nt2)
#pragma unroll
        for (int r = 0; r < 4; ++r) {
          int m = bm + wr * 64 + mt * 16 + 4 * g + r;
          int n = bn + wc * 64 + nt2 * 16 + l15;
          C[(size_t)m * N + n] = f2bf(acc[mt][nt2][r] + bias[n]);
        }
  } else {
    float* C = (float*)Cv;
#pragma unroll
    for (int mt = 0; mt < 4; ++mt)
#pragma unroll
      for (int nt2 = 0; nt2 < 4; ++nt2)
#pragma unroll
        for (int r = 0; r < 4; ++r) {
          int m = bm + wr * 64 + mt * 16 + 4 * g + r;
          int n = bn + wc * 64 + nt2 * 16 + l15;
          C[(size_t)m * N + n] = acc[mt][nt2][r] + bias[n];
        }
  }
}

// ---------------------------------------------------------------------------
// pack_qk: rope + scale(q, incl. log2e) + bf16.
// Qb[h][l][80]; K split: Kmain[h][l][64] (d 0..63) + Ktail[h][blk][tg4][key64]
// in 8-byte units (d 64..79, tg = (d-64)/4).
// ---------------------------------------------------------------------------
__global__ __launch_bounds__(192) void pack_qk_kernel(
    const unsigned short* __restrict__ qkvb, const float* __restrict__ freqs,
    unsigned short* __restrict__ Qb, unsigned short* __restrict__ Kmain,
    unsigned short* __restrict__ Ktail) {
  int l = blockIdx.x;
  __shared__ float cs[40], sn[40];
  if (threadIdx.x < 40) {
    float f = freqs[(size_t)l * 40 + threadIdx.x];
    cs[threadIdx.x] = cosf(f);
    sn[threadIdx.x] = sinf(f);
  }
  __syncthreads();
  int t = threadIdx.x;
  if (t >= 160) return;
  int which = t / 80;              // 0 = q, 1 = k
  int rem   = t % 80;
  int h = rem / 5, pg = rem % 5;
  int d0 = pg * 8;
  const unsigned short* src = qkvb + (size_t)l * QKVN + which * DD + h * HDD;
  union { sv8 v; unsigned short u[8]; } A, B;
  A.v = *(const sv8*)(src + d0);
  B.v = *(const sv8*)(src + d0 + 40);
  float scale = which ? 1.0f : 0.16129822676f;   // q: 1/sqrt(80)*log2(e)
  float lo[8], hi[8];
#pragma unroll
  for (int j = 0; j < 8; ++j) {
    float c = cs[d0 + j], s = sn[d0 + j];
    float a = bf2f(A.u[j]), b = bf2f(B.u[j]);
    lo[j] = (a * c - b * s) * scale;
    hi[j] = (b * c + a * s) * scale;
  }
  union { sv8 v; unsigned int u[4]; } OL, OH;
#pragma unroll
  for (int j = 0; j < 4; ++j) {
    OL.u[j] = cvt_pk_bf16(lo[2 * j], lo[2 * j + 1]);
    OH.u[j] = cvt_pk_bf16(hi[2 * j], hi[2 * j + 1]);
  }
  if (which == 0) {
    unsigned short* dst = Qb + ((size_t)h * LL + l) * HDD;
    *(sv8*)(dst + d0) = OL.v;
    *(sv8*)(dst + d0 + 40) = OH.v;
  } else {
    unsigned short* km = Kmain + ((size_t)h * LL + l) * 64;
    *(sv8*)(km + pg * 8) = OL.v;                 // d0 in 0..32 (main)
    int dh = d0 + 40;
    if (dh < 64) {
      *(sv8*)(km + dh) = OH.v;                   // dh 40,48,56 (main)
    } else {
      // tail: dh = 64 or 72 -> tg0 = (dh-64)/4, units (tg0, tg0+1)
      int blk = l >> 6, key = l & 63;
      int tg0 = (dh - 64) >> 2;
      size_t base = (((size_t)h * 64 + blk) * 4);
      uint2 w0 = make_uint2(OH.u[0], OH.u[1]);   // d dh..dh+3
      uint2 w1 = make_uint2(OH.u[2], OH.u[3]);   // d dh+4..dh+7
      *(uint2*)(Ktail + ((base + tg0) * 64 + key) * 4)     = w0;
      *(uint2*)(Ktail + ((base + tg0 + 1) * 64 + key) * 4) = w1;
    }
  }
}

// ---------------------------------------------------------------------------
// Flash attention: swapped QK^T, exp2-space softmax (no online max),
// in-register P -> PV via 16x16x16 MFMA. Conflict-free LDS. Raw v_exp_f32.
// setprio(1) spans the QK^T->PV compute region. 64 q rows per block,
// 1024 blocks, counted vmcnt(5), 40KB LDS.
// ---------------------------------------------------------------------------
__global__ __launch_bounds__(256) void attn_mfma_kernel(
    const unsigned short* __restrict__ Qb,     // [H][L][80] (pre-scaled)
    const unsigned short* __restrict__ Kmain,  // [H][L][64]
    const unsigned short* __restrict__ Ktail,  // [H][64][4][64] 8B units
    const unsigned short* __restrict__ Vp,     // [H][64][16][80] 8B units
    const int* __restrict__ cu,
    unsigned short* __restrict__ outb) {       // [L][1280] bf16
  __shared__ __attribute__((aligned(16))) unsigned short Ks[2][64 * 64];
  __shared__ __attribute__((aligned(16))) unsigned short Kt[2][4 * 64 * 4];
  __shared__ __attribute__((aligned(16))) unsigned short Vl[2][16 * 80 * 4];
  int tid = threadIdx.x, w = tid >> 6, lane = tid & 63;
  int g = lane >> 4, l15 = lane & 15;

  // XCD-aware bijective swizzle: 1024 blocks, 8 XCDs -> 2 whole heads per XCD
  int bid = blockIdx.x;
  int sw = (bid & 7) * 128 + (bid >> 3);
  int h = sw >> 6;
  int q0 = (sw & 63) * 64;

  int s0 = 0, s1 = LL;
#pragma unroll
  for (int i = 0; i < 4; ++i) {
    int a = cu[i], b = cu[i + 1];
    if (q0 >= a && q0 < b) { s0 = a; s1 = b; }
  }

  // Q fragments (B operand: col=l15=q). rows = q0 + w*16 + l15
  int qrow = q0 + w * 16 + l15;
  const unsigned short* qp = Qb + ((size_t)h * LL + qrow) * HDD;
  sv8 aq[2];
#pragma unroll
  for (int s = 0; s < 2; ++s) aq[s] = *(const sv8*)(qp + s * 32 + g * 8);
  union { sv4 v; uint2 u2; } qt;           // Q tail dims 64..79 (K=16 B-frag)
  qt.u2 = *(const uint2*)(qp + 64 + 4 * g);

  auto STAGE = [&](int buf, int kb) {      // 5 loads per wave (uniform)
    int blk = kb >> 6;
#pragma unroll
    for (int i = 0; i < 5; ++i) {
      int cid = w + 4 * i;                 // 0..19
      if (cid < 8) {                       // Kmain chunk: 8 rows of 128B
        int row = 8 * cid + (lane >> 3);
        int cb = lane & 7;
        GLD_LDS(Kmain + ((size_t)h * LL + kb + row) * 64 + ((cb ^ (row & 7)) * 8),
                Ks[buf] + cid * 512);
      } else if (cid < 10) {               // Ktail: 2 chunks, linear units
        int tc = cid - 8;
        GLD_LDS(Ktail + ((((size_t)h * 64 + blk) * 256) + tc * 128 + 2 * lane) * 4,
                Kt[buf] + tc * 512);
      } else {                             // V: 10 chunks, linear units
        int vc = cid - 10;
        GLD_LDS(Vp + ((((size_t)h * 64 + blk) * 1280) + vc * 128 + 2 * lane) * 4,
                Vl[buf] + vc * 512);
      }
    }
  };

  fv4 o[5];
#pragma unroll
  for (int dt = 0; dt < 5; ++dt) o[dt] = (fv4){0.f, 0.f, 0.f, 0.f};
  float lsum = 0.f;

  int cur = 0;
  STAGE(0, s0);
  if (s0 + 64 < s1) STAGE(1, s0 + 64);
  for (int kb = s0; kb < s1; kb += 64) {
    if (kb + 64 < s1) asm volatile("s_waitcnt vmcnt(5)" ::: "memory");
    else              asm volatile("s_waitcnt vmcnt(0)" ::: "memory");
    SCHEDB();
    asm volatile("s_barrier" ::: "memory");
    const unsigned short* Kc = Ks[cur];
    const unsigned short* Ktc = Kt[cur];
    const unsigned short* Vc = Vl[cur];

    SETPRIO(1);
    // S^T = K Q^T : D[row=key_local][col=q]
    fv4 sf[4];
#pragma unroll
    for (int nt = 0; nt < 4; ++nt) sf[nt] = (fv4){0.f, 0.f, 0.f, 0.f};
#pragma unroll
    for (int s = 0; s < 2; ++s) {
#pragma unroll
      for (int nt = 0; nt < 4; ++nt) {
        int key = nt * 16 + l15;
        sv8 ak = *(const sv8*)(Kc + key * 64 + (((s * 4 + g) ^ (key & 7)) * 8));
        sf[nt] = __builtin_amdgcn_mfma_f32_16x16x32_bf16(ak, aq[s], sf[nt], 0, 0, 0);
      }
    }
#pragma unroll
    for (int nt = 0; nt < 4; ++nt) {       // dims 64..79 via K=16 MFMA
      sv4 akt = *(const sv4*)(Ktc + (g * 64 + nt * 16 + l15) * 4);
      sf[nt] = MFMA16(akt, qt.v, sf[nt]);
    }

    // P = exp2(S^T) stays in-register (C-frag == 16x16x16 A-frag)
#pragma unroll
    for (int nt = 0; nt < 4; ++nt) {
      float p0 = EXP2F(sf[nt][0]);
      float p1 = EXP2F(sf[nt][1]);
      float p2 = EXP2F(sf[nt][2]);
      float p3 = EXP2F(sf[nt][3]);
      lsum += (p0 + p1) + (p2 + p3);
      union { sv4 v; unsigned int u[2]; } pa;
      pa.u[0] = cvt_pk_bf16(p0, p1);
      pa.u[1] = cvt_pk_bf16(p2, p3);
#pragma unroll
      for (int dt = 0; dt < 5; ++dt) {
        sv4 vb4 = *(const sv4*)(Vc + ((nt * 4 + g) * 80 + dt * 16 + l15) * 4);
        o[dt] = MFMA16(pa.v, vb4, o[dt]);
      }
    }
    SETPRIO(0);
    asm volatile("s_waitcnt lgkmcnt(0)" ::: "memory");
    asm volatile("s_barrier" ::: "memory");
    if (kb + 128 < s1) STAGE(cur, kb + 128);
    cur ^= 1;
  }

  // epilogue: reduce lsum across g (all lanes same l15 -> total), route by row
  lsum += __shfl_xor(lsum, 16);
  lsum += __shfl_xor(lsum, 32);
  float inv = 1.f / lsum;
#pragma unroll
  for (int r = 0; r < 4; ++r) {
    float invr = __shfl(inv, 4 * g + r);   // lane with l15 == 4g+r
    int row = q0 + w * 16 + 4 * g + r;
#pragma unroll
    for (int dt = 0; dt < 5; ++dt) {
      outb[(size_t)row * DD + h * HDD + dt * 16 + l15] = f2bf(o[dt][r] * invr);
    }
  }
}

// ---------------------------------------------------------------------------
extern "C" void kernel_launch(void* const* d_in, const int* in_sizes, int n_in,
                              void* d_out, int out_size, void* d_ws, size_t ws_size,
                              hipStream_t stream) {
  const float* x     = (const float*)d_in[0];
  const int*   cu    = (const int*)d_in[1];
  const float* rope  = (const float*)d_in[2];
  const float* Wqkv  = (const float*)d_in[3];
  const float* bqkv  = (const float*)d_in[4];
  const float* Wproj = (const float*)d_in[5];
  const float* bproj = (const float*)d_in[6];
  float* out = (float*)d_out;

  char* ws = (char*)d_ws;
  unsigned short* qkvb   = (unsigned short*)ws;                 // 31,457,280 B (q/k planes used)
  unsigned short* attn_b = (unsigned short*)ws;                 // alias (qkvb dead by then)
  unsigned short* xb     = (unsigned short*)(ws + 31457280);    // 10,485,760
  unsigned short* Wqkvb  = (unsigned short*)(ws + 41943040);    //  9,830,400
  unsigned short* Wprojb = (unsigned short*)(ws + 51773440);    //  3,276,800
  unsigned short* Kmain  = (unsigned short*)(ws + 55050240);    //  8,388,608 ([H][L][64])
  unsigned short* Ktail  = (unsigned short*)(ws + 63438848);    //  2,097,152 ([H][64][4][64]x8B)
  unsigned short* Vp     = (unsigned short*)(ws + 65536000);    // 10,485,760 ([H][64][16][80]x8B)
  unsigned short* Qb     = xb;                                  // alias (xb dead after gemm1)

  // casts (one launch)
  {
    int n8 = LL * DD / 8 + QKVN * DD / 8 + DD * DD / 8;
    cast3_kernel<<<(n8 + 255) / 256, 256, 0, stream>>>(x, Wqkv, Wproj, xb, Wqkvb, Wprojb);
  }

  // qkv = x @ Wqkv^T + b  (bf16): q/k planes -> qkvb, v plane -> Vp directly
  gemm256_bf16_kernel<<<240, 512, 0, stream>>>(
      xb, Wqkvb, bqkv, qkvb, Vp, LL, QKVN, DD);

  // rope + pack (V already packed by the GEMM epilogue)
  pack_qk_kernel<<<LL, 192, 0, stream>>>(qkvb, rope, Qb, Kmain, Ktail);

  // attention
  attn_mfma_kernel<<<1024, 256, 0, stream>>>(Qb, Kmain, Ktail, Vp, cu, attn_b);

  // out = attn @ Wproj^T + b  (fp32 out): 128^2 tile, 320 blocks
  gemm_bf16_kernel<<<dim3(DD / 128, LL / 128), 256, 0, stream>>>(
      attn_b, Wprojb, bproj, out, LL, DD, DD, 0);
}